// Round 1
// baseline (404.401 us; speedup 1.0000x reference)
//
#include <hip/hip_runtime.h>

typedef float f32x4 __attribute__((ext_vector_type(4)));
typedef short short8 __attribute__((ext_vector_type(8)));
typedef unsigned short u16;
typedef unsigned int u32;

#define NPG 69   // nodes per graph (68 landmarks + master)
#define LM 68    // landmark count / master index
#define HID 64

// GCN normalization constants (fixed topology):
// landmark deg=4 -> dis=0.5 ; master deg=69 -> dis=1/sqrt(69)
#define CLL 0.25f                      // landmark<-landmark (and landmark self)
#define CML 0.06019292654288460f       // 0.5/sqrt(69): master<->landmark
#define SELFM 0.014492753623188406f    // 1/69: master self

__device__ __forceinline__ u16 f2bf(float x) {
  u32 b = __float_as_uint(x);
  return (u16)((b + 0x7FFFu + ((b >> 16) & 1u)) >> 16);
}

// Pre-swizzle the 7 HID x HID weight matrices (6 mid + 1 last) into bf16
// B-fragment order for mfma_f32_16x16x32_bf16:
//   frag[(l*4+nt)*2+ks][lane][j] = W_l[ks*32 + (lane>>4)*8 + j][nt*16 + (lane&15)]
__global__ void prep_frags(const float* __restrict__ midW,
                           const float* __restrict__ lastW,
                           u16* __restrict__ frag) {
  const int total = 7 * 4 * 2 * 64;
  for (int u = blockIdx.x * blockDim.x + threadIdx.x; u < total;
       u += gridDim.x * blockDim.x) {
    const int lane = u & 63;
    const int t = u >> 6;
    const int ks = t & 1;
    const int nt = (t >> 1) & 3;
    const int l = t >> 3;  // 0..6
    const float* W = (l < 6) ? (midW + l * 4096) : lastW;
    const int col = nt * 16 + (lane & 15);
    const int kb = ks * 32 + (lane >> 4) * 8;
    u16* dst = frag + (size_t)u * 8;
#pragma unroll
    for (int j = 0; j < 8; ++j) dst[j] = f2bf(W[(kb + j) * 64 + col]);
  }
}

__launch_bounds__(256)
__global__ void gcn_fused(
    const float* __restrict__ x,
    const float* __restrict__ cfW, const float* __restrict__ cfb,
    const float* __restrict__ cmb, const float* __restrict__ clb,
    const float* __restrict__ bng, const float* __restrict__ bnb,
    const float* __restrict__ bnm, const float* __restrict__ bnv,
    const float* __restrict__ aW1, const float* __restrict__ ab1,
    const float* __restrict__ aW2, const float* __restrict__ ab2,
    const float* __restrict__ f1W, const float* __restrict__ f1b,
    const float* __restrict__ f2W, const float* __restrict__ f2b,
    const u16* __restrict__ frag,
    float* __restrict__ out) {
  // LDS. All f32 tiles use stride 68 (=4 mod 32) -> 16B aligned b128 access,
  // conflict-free across the (node,feat-quad) thread mapping.
  __shared__ float xl[NPG * 4];          // staged input features
  __shared__ u16 hb[80 * 64];            // bf16 h, XOR-swizzled, rows 69..79 = 0 pad
  __shared__ float hf[NPG * 68];         // fp32 h (residual/readout master copy)
  __shared__ float tl[NPG * 68];         // fp32 t = h @ W (pre-aggregation)
  __shared__ float psum[16 * 68];        // partial sums (master agg / readout)
  __shared__ float gv[192];              // readout concat [mean | max | master*att]

  const int tid = threadIdx.x;
  const int g = blockIdx.x;
  const int lane = tid & 63;
  const int wv = tid >> 6;    // wave id = N-tile for MFMA
  const int p15 = lane & 15;
  const int qg = lane >> 4;

  // epilogue thread mapping: 16 feat-quads x 16 node-chunks
  const int ef0 = (tid & 15) * 4;
  const int ec = tid >> 4;

  // zero bf16 buffer (pad rows must stay 0 for MFMA A-reads)
  for (int i = tid; i < 80 * 32; i += 256) ((u32*)hb)[i] = 0u;
  if (tid < NPG)
    *(f32x4*)&xl[tid * 4] = *(const f32x4*)&x[((size_t)g * NPG + tid) * 4];
  __syncthreads();

  // ---- layer 0: t = x @ W_first  (exact fp32, K=4)
  {
    float w0[4];
#pragma unroll
    for (int k = 0; k < 4; ++k) w0[k] = cfW[k * 64 + lane];
    for (int n = wv; n < NPG; n += 4) {
      const f32x4 xv = *(const f32x4*)&xl[n * 4];
      tl[n * 68 + lane] = xv[0] * w0[0] + xv[1] * w0[1] + xv[2] * w0[2] + xv[3] * w0[3];
    }
  }
  __syncthreads();

  // ---- shared epilogue: aggregation + bias + relu + [bn] + [residual]
  // writes hf (fp32) and hb (bf16, swizzled) for the next layer's MFMA
  auto epilogue = [&](const float* bp, int bni, bool resid) {
    const f32x4 bias = *(const f32x4*)&bp[ef0];
    f32x4 sc, sh;
    if (bni >= 0) {
      const f32x4 gm = *(const f32x4*)&bng[bni * 64 + ef0];
      const f32x4 bt = *(const f32x4*)&bnb[bni * 64 + ef0];
      const f32x4 mu = *(const f32x4*)&bnm[bni * 64 + ef0];
      const f32x4 vr = *(const f32x4*)&bnv[bni * 64 + ef0];
#pragma unroll
      for (int e = 0; e < 4; ++e) {
        sc[e] = gm[e] / sqrtf(vr[e] + 1e-5f);
        sh[e] = bt[e] - mu[e] * sc[e];
      }
    }
    const f32x4 tm = *(const f32x4*)&tl[LM * 68 + ef0];  // master row of t
    f32x4 ms = {0.f, 0.f, 0.f, 0.f};
#pragma unroll
    for (int it = 0; it < 5; ++it) {
      const int n = ec + it * 16;
      if (n < LM) {
        const int nm = (n == 0) ? 67 : n - 1;
        const int np = (n == 67) ? 0 : n + 1;
        const f32x4 ta = *(const f32x4*)&tl[nm * 68 + ef0];
        const f32x4 tb = *(const f32x4*)&tl[np * 68 + ef0];
        const f32x4 ts = *(const f32x4*)&tl[n * 68 + ef0];
        f32x4 o;
#pragma unroll
        for (int e = 0; e < 4; ++e) {
          ms[e] += ts[e];
          float v = CLL * (ta[e] + tb[e] + ts[e]) + CML * tm[e] + bias[e];
          v = fmaxf(v, 0.f);
          if (bni >= 0) v = v * sc[e] + sh[e];
          if (resid) v += hf[n * 68 + ef0 + e];
          o[e] = v;
        }
        *(f32x4*)&hf[n * 68 + ef0] = o;
        const int hbase = (n * 64 + ef0) ^ ((n & 7) << 3);  // half-index swizzle
        *(u32*)&hb[hbase] = (u32)f2bf(o[0]) | ((u32)f2bf(o[1]) << 16);
        *(u32*)&hb[hbase + 2] = (u32)f2bf(o[2]) | ((u32)f2bf(o[3]) << 16);
      }
    }
    *(f32x4*)&psum[ec * 68 + ef0] = ms;
    __syncthreads();
    if (tid < 16) {  // master row: needs sum over all 68 landmark rows of t
      const int f0 = tid * 4;  // == this thread's ef0
      f32x4 s = {0.f, 0.f, 0.f, 0.f};
#pragma unroll
      for (int c2 = 0; c2 < 16; ++c2) {
        const f32x4 v = *(const f32x4*)&psum[c2 * 68 + f0];
#pragma unroll
        for (int e = 0; e < 4; ++e) s[e] += v[e];
      }
      f32x4 o;
#pragma unroll
      for (int e = 0; e < 4; ++e) {
        float v = CML * s[e] + SELFM * tm[e] + bias[e];
        v = fmaxf(v, 0.f);
        if (bni >= 0) v = v * sc[e] + sh[e];
        if (resid) v += hf[LM * 68 + f0 + e];
        o[e] = v;
      }
      *(f32x4*)&hf[LM * 68 + f0] = o;
      const int hbase = (LM * 64 + f0) ^ ((LM & 7) << 3);
      *(u32*)&hb[hbase] = (u32)f2bf(o[0]) | ((u32)f2bf(o[1]) << 16);
      *(u32*)&hb[hbase + 2] = (u32)f2bf(o[2]) | ((u32)f2bf(o[3]) << 16);
    }
    __syncthreads();
  };

  epilogue(cfb, 0, false);

  // ---- layers 1..7: t = h @ W via bf16 MFMA, then epilogue
  for (int l = 1; l <= 7; ++l) {
    // this wave's B fragments (N-tile = wv), both K-steps
    const u16* fb = frag + ((((size_t)(l - 1) * 4 + wv) * 2) * 64 + lane) * 8;
    const short8 b0 = *(const short8*)fb;
    const short8 b1 = *(const short8*)(fb + 512);
    const int col = wv * 16 + p15;
#pragma unroll
    for (int mt = 0; mt < 5; ++mt) {
      const int row = mt * 16 + p15;
      const int swz = (row & 7) << 3;
      const short8 a0 = *(const short8*)&hb[(row * 64 + qg * 8) ^ swz];
      const short8 a1 = *(const short8*)&hb[(row * 64 + 32 + qg * 8) ^ swz];
      f32x4 acc = {0.f, 0.f, 0.f, 0.f};
      acc = __builtin_amdgcn_mfma_f32_16x16x32_bf16(a0, b0, acc, 0, 0, 0);
      acc = __builtin_amdgcn_mfma_f32_16x16x32_bf16(a1, b1, acc, 0, 0, 0);
      const int rb = mt * 16 + qg * 4;
#pragma unroll
      for (int r = 0; r < 4; ++r)
        if (rb + r < NPG) tl[(rb + r) * 68 + col] = acc[r];
    }
    __syncthreads();
    if (l < 7) epilogue(cmb + (l - 1) * 64, l, true);
    else epilogue(clb, -1, false);
  }

  // ---- readout: mean/max over landmarks, gated master, fc head
  {
    float* pmax = tl;  // reuse t buffer
    f32x4 s = {0.f, 0.f, 0.f, 0.f};
    f32x4 m = {-3.402823466e38f, -3.402823466e38f, -3.402823466e38f, -3.402823466e38f};
#pragma unroll
    for (int it = 0; it < 5; ++it) {
      const int n = ec + it * 16;
      if (n < LM) {
        const f32x4 v = *(const f32x4*)&hf[n * 68 + ef0];
#pragma unroll
        for (int e = 0; e < 4; ++e) {
          s[e] += v[e];
          m[e] = fmaxf(m[e], v[e]);
        }
      }
    }
    *(f32x4*)&psum[ec * 68 + ef0] = s;
    *(f32x4*)&pmax[ec * 68 + ef0] = m;
  }
  __syncthreads();
  if (tid < 16) {
    const float* pmax = tl;
    const int f0 = tid * 4;
    f32x4 s = {0.f, 0.f, 0.f, 0.f};
    f32x4 m = {-3.402823466e38f, -3.402823466e38f, -3.402823466e38f, -3.402823466e38f};
#pragma unroll
    for (int c2 = 0; c2 < 16; ++c2) {
      const f32x4 a = *(const f32x4*)&psum[c2 * 68 + f0];
      const f32x4 b = *(const f32x4*)&pmax[c2 * 68 + f0];
#pragma unroll
      for (int e = 0; e < 4; ++e) {
        s[e] += a[e];
        m[e] = fmaxf(m[e], b[e]);
      }
    }
#pragma unroll
    for (int e = 0; e < 4; ++e) {
      gv[f0 + e] = s[e] * (1.f / 68.f);
      gv[64 + f0 + e] = m[e];
    }
  }
  __syncthreads();
  if (tid < 64) {  // attention gate on master features
    float z = ab1[tid];
    for (int k = 0; k < 64; ++k) z += hf[LM * 68 + k] * aW1[k * 64 + tid];
    z = fmaxf(z, 0.f);
    float pr = z * aW2[tid];
#pragma unroll
    for (int off = 32; off > 0; off >>= 1) pr += __shfl_xor(pr, off, 64);
    const float att = 1.f / (1.f + expf(-(pr + ab2[0])));
    gv[128 + tid] = hf[LM * 68 + tid] * att;
  }
  __syncthreads();
  if (tid < 64) {  // fc1 + relu + fc2
    float a1 = f1b[tid];
    for (int i = 0; i < 192; ++i) a1 += gv[i] * f1W[i * 64 + tid];
    const float y = fmaxf(a1, 0.f);
    float po[7];
#pragma unroll
    for (int o = 0; o < 7; ++o) po[o] = y * f2W[tid * 7 + o];
#pragma unroll
    for (int o = 0; o < 7; ++o) {
#pragma unroll
      for (int off = 32; off > 0; off >>= 1) po[o] += __shfl_xor(po[o], off, 64);
    }
    if (tid == 0) {
#pragma unroll
      for (int o = 0; o < 7; ++o) out[(size_t)g * 7 + o] = po[o] + f2b[o];
    }
  }
}

extern "C" void kernel_launch(void* const* d_in, const int* in_sizes, int n_in,
                              void* d_out, int out_size, void* d_ws, size_t ws_size,
                              hipStream_t stream) {
  const float* x = (const float*)d_in[0];
  // d_in[1..3] (edge_index/batch/master_mask) encode the fixed topology -> unused
  const float* cfW = (const float*)d_in[4];
  const float* cfb = (const float*)d_in[5];
  const float* cmW = (const float*)d_in[6];
  const float* cmb = (const float*)d_in[7];
  const float* clW = (const float*)d_in[8];
  const float* clb = (const float*)d_in[9];
  const float* bng = (const float*)d_in[10];
  const float* bnb = (const float*)d_in[11];
  const float* bnm = (const float*)d_in[12];
  const float* bnv = (const float*)d_in[13];
  const float* aW1 = (const float*)d_in[14];
  const float* ab1 = (const float*)d_in[15];
  const float* aW2 = (const float*)d_in[16];
  const float* ab2 = (const float*)d_in[17];
  const float* f1W = (const float*)d_in[18];
  const float* f1b = (const float*)d_in[19];
  const float* f2W = (const float*)d_in[20];
  const float* f2b = (const float*)d_in[21];

  u16* frag = (u16*)d_ws;  // needs 7*4*2*64*8*2 = 57344 bytes
  const int ngraphs = out_size / 7;

  prep_frags<<<dim3(14), dim3(256), 0, stream>>>(cmW, clW, frag);
  gcn_fused<<<dim3(ngraphs), dim3(256), 0, stream>>>(
      x, cfW, cfb, cmb, clb, bng, bnb, bnm, bnv,
      aW1, ab1, aW2, ab2, f1W, f1b, f2W, f2b, frag, (float*)d_out);
}